// Round 5
// baseline (95.575 us; speedup 1.0000x reference)
//
#include <hip/hip_runtime.h>
#include <hip/hip_bf16.h>

typedef unsigned short u16;
typedef __attribute__((ext_vector_type(8))) short short8;    // 8 bf16 (4 VGPR) MFMA A/B frag
typedef __attribute__((ext_vector_type(4))) float f32x4;     // MFMA C/D frag
typedef __attribute__((ext_vector_type(8))) unsigned short u16x8;

#define MDIM 4096
#define NDIM 1024
#define KDIM 2048
#define BM 256       // rows per block
#define BNS 64       // spatial cols per block (x4 gates)
#define BK 64
#define NT (KDIM / BK)   // 32 K-tiles

#define G_I 0
#define G_F 1
#define G_C 2
#define G_O 3

// fp32 -> bf16 round-to-nearest-even
static __device__ __forceinline__ u16 f2b(float f) {
    unsigned u = __builtin_bit_cast(unsigned, f);
    unsigned r = u + 0x7fffu + ((u >> 16) & 1u);
    return (u16)(r >> 16);
}

static __device__ __forceinline__ float sigm(float x) {
    return 1.0f / (1.0f + __expf(-x));
}

// async global->LDS 16B copy. LDS dest wave-uniform; HW adds lane*16.
static __device__ __forceinline__ void gload16(const void* g, void* l) {
    __builtin_amdgcn_global_load_lds(
        (__attribute__((address_space(1))) void*)g,
        (__attribute__((address_space(3))) void*)l, 16, 0, 0);
}

// inline-asm LDS read: opaque to compiler aliasing; pair with counted
// s_waitcnt lgkmcnt + sched_barrier(0) before the consuming MFMA (rule #18).
template <int IMM>
static __device__ __forceinline__ short8 ds_read_imm(unsigned addr) {
    short8 r;
    asm volatile("ds_read_b128 %0, %1 offset:%2"
                 : "=&v"(r) : "v"(addr), "i"(IMM));
    return r;
}

// ---------------------------------------------------------------------------
// Pack x,h -> bf16 xh workspace, tiled [mblk 16][kt 32][256][64] with XOR slot
// swizzle pre-applied: element (row,k) at row*64 + (((k>>3)^row)&7)*8 + (k&7)
// ---------------------------------------------------------------------------
__global__ void conv_xh_kernel(const float* __restrict__ x,
                               const float* __restrict__ h,
                               u16* __restrict__ xh_ws) {
    const int kblk = blockIdx.x;  // 0..31
    const int mblk = blockIdx.y;  // 0..15
    u16* dst = xh_ws + (size_t)(mblk * 32 + kblk) * (BM * BK);
    const float* src0;
    int kofs;
    if (kblk < 16) { src0 = x; kofs = kblk * 64; }
    else           { src0 = h; kofs = kblk * 64 - 1024; }
    for (int i = threadIdx.x; i < BM * 8; i += 256) {
        int mr = i >> 3, s = i & 7;
        const float* p = src0 + (size_t)(mblk * BM + mr) * 1024 + kofs + s * 8;
        float4 a = reinterpret_cast<const float4*>(p)[0];
        float4 b = reinterpret_cast<const float4*>(p)[1];
        u16x8 o;
        o[0] = f2b(a.x); o[1] = f2b(a.y); o[2] = f2b(a.z); o[3] = f2b(a.w);
        o[4] = f2b(b.x); o[5] = f2b(b.y); o[6] = f2b(b.z); o[7] = f2b(b.w);
        *reinterpret_cast<u16x8*>(dst + mr * 64 + ((s ^ (mr & 7)) << 3)) = o;
    }
}

// ---------------------------------------------------------------------------
// Transpose-convert W_g [K][N] fp32 -> bf16 [g][nblk 16][kt 32][64 n][64 k],
// same XOR slot swizzle on the k axis within each 64-row.
// ---------------------------------------------------------------------------
__global__ void conv_w_kernel(const float* __restrict__ Wi,
                              const float* __restrict__ Wf,
                              const float* __restrict__ Wc,
                              const float* __restrict__ Wo,
                              u16* __restrict__ w_ws) {
    const int kblk = blockIdx.x;  // 0..31
    const int nblk = blockIdx.y;  // 0..15
    const int g    = blockIdx.z;  // 0..3
    const float* W = (g == 0) ? Wi : (g == 1) ? Wf : (g == 2) ? Wc : Wo;
    u16* dst = w_ws + (size_t)((g * 16 + nblk) * 32 + kblk) * (BNS * BK);
    const int nr = threadIdx.x & 63;
    const int s0 = threadIdx.x >> 6;   // 0..3
    const int n  = nblk * 64 + nr;
    for (int s = s0; s < 8; s += 4) {
        const float* p = W + (size_t)(kblk * 64 + s * 8) * 1024 + n;
        u16x8 o;
#pragma unroll
        for (int j = 0; j < 8; ++j) o[j] = f2b(p[(size_t)j * 1024]);
        *reinterpret_cast<u16x8*>(dst + nr * 64 + ((s ^ (nr & 7)) << 3)) = o;
    }
}

// ---------------------------------------------------------------------------
// Fused 4-gate GEMM + LSTM epilogue. 8 waves (4M x 2N), tile 256m x 64n x 4g.
// Register-pipelined 4-phase schedule: phase p issues ds_reads for phase p+1's
// fragments (double-banked afr/bfr), MFMAs phase p, waits counted lgkmcnt(R)
// covering only the PREVIOUS phase's reads. Staging 1 K-tile ahead; counted
// vmcnt(6)/vmcnt(2) tail drains with >=1-phase slack; vmcnt(0) last tile only.
// ---------------------------------------------------------------------------
__global__ __launch_bounds__(512, 2) void lstm_gemm_kernel(
    const u16* __restrict__ xh_ws, const u16* __restrict__ w_ws,
    const float* __restrict__ c_in,
    const float* __restrict__ b_i, const float* __restrict__ b_f,
    const float* __restrict__ b_c, const float* __restrict__ b_o,
    float* __restrict__ h_out, float* __restrict__ c_out) {
    // per buffer: A 256x64 (16384 u16) + B 4x64x64 (16384 u16); x2 = 128 KiB
    __shared__ u16 lds[2 * 32768];

    const int nblk = blockIdx.x;   // 0..15
    const int mblk = blockIdx.y;   // 0..15
    const int t    = threadIdx.x;
    const int lane = t & 63;
    const int w    = t >> 6;       // 0..7
    const int wq   = w >> 1;       // m-quadrant 0..3 (64 rows each)
    const int wn   = w & 1;        // n-half 0..1 (32 cols each)
    const int l15  = lane & 15;
    const int l4   = lane >> 4;

    const size_t bstr = (size_t)NT * 4096;   // w_ws: per-(g,nblk) run of K-tiles
    const u16* aSrc = xh_ws + (size_t)mblk * (NT * 16384) + (w * 2) * 512 + lane * 8;
    const u16* bSrc = w_ws + (size_t)nblk * bstr + w * 512 + lane * 8;
    u16* aDst = lds + (w * 2) * 512;           // + c*32768 + half*8192 (+512)
    u16* bDst = lds + 16384 + w * 512;         // + c*32768 + pb*8192 (+4096)

    // LDS read byte-addresses for asm ds_read (swizzle folded into slot).
    const unsigned lbase = (unsigned)(uintptr_t)&lds[0];
    unsigned slot[2];
    slot[0] = (unsigned)((((0 * 4 + l4) ^ l15) & 7) * 16);
    slot[1] = (unsigned)((((1 * 4 + l4) ^ l15) & 7) * 16);
    const unsigned aCom = lbase + wq * 8192 + l15 * 128;
    const unsigned bCom = lbase + 32768 + wn * 4096 + l15 * 128;
    unsigned aReg[2][2], bReg[2][2];           // [buf c][ks]
#pragma unroll
    for (int c = 0; c < 2; ++c)
#pragma unroll
        for (int ks = 0; ks < 2; ++ks) {
            aReg[c][ks] = aCom + c * 65536 + slot[ks];
            bReg[c][ks] = bCom + c * 65536 + slot[ks];
        }

    f32x4 acc[4][4][2] = {};   // [gate][mf][nf]
    short8 afr0[4][2], afr1[4][2];   // A frag banks (per-tile parity)
    short8 bfr0[2][2], bfr1[2][2];   // B frag banks (per-phase parity)

// ---- asm read clusters (BUF/BNK are literal tokens 0 or 1) ----
#define RD_A_KS(BUF, ks)                                                       \
    { afr##BUF[0][ks] = ds_read_imm<0>(aReg[BUF][ks]);                         \
      afr##BUF[1][ks] = ds_read_imm<2048>(aReg[BUF][ks]);                      \
      afr##BUF[2][ks] = ds_read_imm<4096>(aReg[BUF][ks]);                      \
      afr##BUF[3][ks] = ds_read_imm<6144>(aReg[BUF][ks]); }

#define RD_B(G, BUF, BNK)                                                      \
    { bfr##BNK[0][0] = ds_read_imm<(G)*8192 + 0>(bReg[BUF][0]);                \
      bfr##BNK[1][0] = ds_read_imm<(G)*8192 + 2048>(bReg[BUF][0]);             \
      bfr##BNK[0][1] = ds_read_imm<(G)*8192 + 0>(bReg[BUF][1]);                \
      bfr##BNK[1][1] = ds_read_imm<(G)*8192 + 2048>(bReg[BUF][1]); }

// ---- staging: 2 x global_load_lds (16B) per chunk per thread ----
#define STAGE_A(c, kt, half)                                                   \
    { const u16* s_ = aSrc + (kt) * 16384 + (half) * 8192;                     \
      u16* d_ = aDst + (c) * 32768 + (half) * 8192;                            \
      gload16(s_, d_); gload16(s_ + 512, d_ + 512); }

#define STAGE_B(c, kt, pb)                                                     \
    { const u16* s_ = bSrc + (size_t)(pb) * 2 * 16 * bstr + (kt) * 4096;       \
      u16* d_ = bDst + (c) * 32768 + (pb) * 8192;                              \
      gload16(s_, d_); gload16(s_ + 16 * bstr, d_ + 4096); }

#define VMW(N) asm volatile("s_waitcnt vmcnt(" #N ")" ::: "memory")
#define LGKM(N) asm volatile("s_waitcnt lgkmcnt(" #N ")" ::: "memory")
#define SB0 __builtin_amdgcn_sched_barrier(0)
#define BAR __builtin_amdgcn_s_barrier()

#define MFMA16(G, ABUF, BBNK)                                                  \
    _Pragma("unroll") for (int ks = 0; ks < 2; ++ks)                           \
    _Pragma("unroll") for (int mf = 0; mf < 4; ++mf)                           \
    _Pragma("unroll") for (int nf = 0; nf < 2; ++nf)                           \
        acc[G][mf][nf] = __builtin_amdgcn_mfma_f32_16x16x32_bf16(              \
            afr##ABUF[mf][ks], bfr##BBNK[nf][ks], acc[G][mf][nf], 0, 0, 0);

// One K-tile = 4 gate-phases. c = this tile's buffer (literal 0/1), nc = c^1.
// Frag banks: afr bank == tile buffer; bfr bank alternates per phase.
// Reads per phase: 4 / 4 / 8 / 8. lgkm outstanding entering phases:
// {12,4,4,8} -> LGKM(4)/(4)/(8)/(12) drain exactly the consumed frags.
#define TILE(c, nc, kt, st)                                                    \
  { /* ph0: MFMA gate0 (afr c, bfr bank0) */                                   \
    if (st) { STAGE_A(nc, (kt) + 1, 0); STAGE_A(nc, (kt) + 1, 1);              \
              STAGE_B(nc, (kt) + 1, 0); }                                      \
    RD_B(1, c, 1);                                                             \
    LGKM(4); SB0; BAR; SB0;                                                    \
    __builtin_amdgcn_s_setprio(1); MFMA16(0, c, 0);                            \
    __builtin_amdgcn_s_setprio(0); SB0;                                        \
    if (st) { VMW(6); } else { VMW(0); }                                       \
    BAR;                                                                       \
    /* ph1: MFMA gate1 (afr c, bfr bank1) */                                   \
    if (st) { STAGE_B(nc, (kt) + 1, 1); }                                      \
    RD_B(2, c, 0);                                                             \
    LGKM(4); SB0; BAR; SB0;                                                    \
    __builtin_amdgcn_s_setprio(1); MFMA16(1, c, 1);                            \
    __builtin_amdgcn_s_setprio(0); SB0;                                        \
    VMW(2);                                                                    \
    BAR;                                                                       \
    /* ph2: MFMA gate2 (afr c, bfr bank0); prefetch A(t+1) ks0 */              \
    RD_B(3, c, 1);                                                             \
    RD_A_KS(nc, 0);                                                            \
    LGKM(8); SB0; BAR; SB0;                                                    \
    __builtin_amdgcn_s_setprio(1); MFMA16(2, c, 0);                            \
    __builtin_amdgcn_s_setprio(0); SB0;                                        \
    BAR;                                                                       \
    /* ph3: MFMA gate3 (afr c, bfr bank1); prefetch A(t+1) ks1 + Bg0(t+1) */   \
    RD_A_KS(nc, 1);                                                            \
    RD_B(0, nc, 0);                                                            \
    LGKM(12); SB0; BAR; SB0;                                                   \
    __builtin_amdgcn_s_setprio(1); MFMA16(3, c, 1);                            \
    __builtin_amdgcn_s_setprio(0); SB0;                                        \
    BAR; }

    // ---- prologue: tile 0 fully staged + its ph0 frags pre-read ----
    STAGE_A(0, 0, 0);
    STAGE_A(0, 0, 1);
    STAGE_B(0, 0, 0);
    STAGE_B(0, 0, 1);
    VMW(0);
    BAR;
    RD_A_KS(0, 0);
    RD_A_KS(0, 1);
    RD_B(0, 0, 0);   // gate0 frags -> bfr bank0

#pragma unroll 1
    for (int ut = 0; ut < 16; ++ut) {
        const int kt0 = ut * 2;
        TILE(0, 1, kt0, 1)
        TILE(1, 0, kt0 + 1, (ut < 15))
    }

    // drain dangling last-tile prefetch reads before regs get reused
    LGKM(0); SB0;

    // ---- fused LSTM epilogue (all 4 gates wave-local) ----
    const int mBase = mblk * BM + wq * 64;
    const int nBase = nblk * BNS + wn * 32;
#pragma unroll
    for (int nf = 0; nf < 2; ++nf) {
        int n = nBase + nf * 16 + l15;
        float vbi = b_i[n], vbf = b_f[n], vbc = b_c[n], vbo = b_o[n];
#pragma unroll
        for (int mf = 0; mf < 4; ++mf) {
#pragma unroll
            for (int r = 0; r < 4; ++r) {
                int m = mBase + mf * 16 + l4 * 4 + r;
                size_t idx = (size_t)m * NDIM + n;
                float gi = sigm(acc[G_I][mf][nf][r] + vbi);
                float gf = sigm(acc[G_F][mf][nf][r] + vbf);
                float gc = tanhf(acc[G_C][mf][nf][r] + vbc);
                float go = sigm(acc[G_O][mf][nf][r] + vbo);
                float ct = gf * c_in[idx] + gi * gc;
                h_out[idx] = go * tanhf(ct);
                c_out[idx] = ct;
            }
        }
    }
#undef RD_A_KS
#undef RD_B
#undef STAGE_A
#undef STAGE_B
#undef VMW
#undef LGKM
#undef SB0
#undef BAR
#undef MFMA16
#undef TILE
}

extern "C" void kernel_launch(void* const* d_in, const int* in_sizes, int n_in,
                              void* d_out, int out_size, void* d_ws, size_t ws_size,
                              hipStream_t stream) {
    const float* x   = (const float*)d_in[0];
    const float* h   = (const float*)d_in[1];
    const float* c   = (const float*)d_in[2];
    const float* Wi  = (const float*)d_in[3];
    const float* Wf  = (const float*)d_in[4];
    const float* Wc  = (const float*)d_in[5];
    const float* Wo  = (const float*)d_in[6];
    const float* bi  = (const float*)d_in[7];
    const float* bf_ = (const float*)d_in[8];
    const float* bc  = (const float*)d_in[9];
    const float* bo  = (const float*)d_in[10];

    float* hout = (float*)d_out;
    float* cout = hout + (size_t)MDIM * NDIM;

    u16* xh_ws = (u16*)d_ws;                       // bf16 xh, 16.78 MB
    u16* w_ws  = xh_ws + (size_t)MDIM * KDIM;      // bf16 W^T, 16.78 MB

    conv_xh_kernel<<<dim3(32, 16), 256, 0, stream>>>(x, h, xh_ws);
    conv_w_kernel<<<dim3(32, 16, 4), 256, 0, stream>>>(Wi, Wf, Wc, Wo, w_ws);
    lstm_gemm_kernel<<<dim3(16, 16), 512, 0, stream>>>(
        xh_ws, w_ws, c, bi, bf_, bc, bo, hout, cout);
}

// Round 6
// 94.924 us; speedup vs baseline: 1.0069x; 1.0069x over previous
//
#include <hip/hip_runtime.h>
#include <hip/hip_bf16.h>

typedef unsigned short u16;
typedef __attribute__((ext_vector_type(8))) short short8;    // 8 bf16 (4 VGPR) MFMA A/B frag
typedef __attribute__((ext_vector_type(4))) float f32x4;     // MFMA C/D frag
typedef __attribute__((ext_vector_type(8))) unsigned short u16x8;

#define MDIM 4096
#define NDIM 1024
#define KDIM 2048
#define BM 128       // rows per block
#define BNS 32       // spatial cols per block (x4 gates = 128 effective N)
#define BK 64
#define NT (KDIM / BK)   // 32 K-tiles

#define G_I 0
#define G_F 1
#define G_C 2
#define G_O 3

// fp32 -> bf16 round-to-nearest-even
static __device__ __forceinline__ u16 f2b(float f) {
    unsigned u = __builtin_bit_cast(unsigned, f);
    unsigned r = u + 0x7fffu + ((u >> 16) & 1u);
    return (u16)(r >> 16);
}

static __device__ __forceinline__ float sigm(float x) {
    return 1.0f / (1.0f + __expf(-x));
}

// async global->LDS 16B copy. LDS dest wave-uniform; HW adds lane*16.
static __device__ __forceinline__ void gload16(const void* g, void* l) {
    __builtin_amdgcn_global_load_lds(
        (__attribute__((address_space(1))) void*)g,
        (__attribute__((address_space(3))) void*)l, 16, 0, 0);
}

// ---------------------------------------------------------------------------
// Pack x,h -> bf16 xh workspace, tiled [mblk 32][kblk 32][128][64] with XOR
// slot swizzle: element (row,k) at row*64 + (((k>>3)^row)&7)*8 + (k&7)
// ---------------------------------------------------------------------------
__global__ void conv_xh_kernel(const float* __restrict__ x,
                               const float* __restrict__ h,
                               u16* __restrict__ xh_ws) {
    const int kblk = blockIdx.x;  // 0..31
    const int mblk = blockIdx.y;  // 0..31
    u16* dst = xh_ws + (size_t)(mblk * 32 + kblk) * (BM * BK);
    const float* src0;
    int kofs;
    if (kblk < 16) { src0 = x; kofs = kblk * 64; }
    else           { src0 = h; kofs = kblk * 64 - 1024; }
    for (int i = threadIdx.x; i < BM * 8; i += 256) {
        int mr = i >> 3, s = i & 7;
        const float* p = src0 + (size_t)(mblk * BM + mr) * 1024 + kofs + s * 8;
        float4 a = reinterpret_cast<const float4*>(p)[0];
        float4 b = reinterpret_cast<const float4*>(p)[1];
        u16x8 o;
        o[0] = f2b(a.x); o[1] = f2b(a.y); o[2] = f2b(a.z); o[3] = f2b(a.w);
        o[4] = f2b(b.x); o[5] = f2b(b.y); o[6] = f2b(b.z); o[7] = f2b(b.w);
        *reinterpret_cast<u16x8*>(dst + mr * 64 + ((s ^ (mr & 7)) << 3)) = o;
    }
}

// ---------------------------------------------------------------------------
// Transpose-convert W_g [K][N] fp32 -> bf16 [g][nblk 32][kblk 32][32 n][64 k],
// same XOR slot swizzle on the k axis within each 64-row.
// ---------------------------------------------------------------------------
__global__ void conv_w_kernel(const float* __restrict__ Wi,
                              const float* __restrict__ Wf,
                              const float* __restrict__ Wc,
                              const float* __restrict__ Wo,
                              u16* __restrict__ w_ws) {
    const int kblk = blockIdx.x;  // 0..31
    const int nblk = blockIdx.y;  // 0..31
    const int g    = blockIdx.z;  // 0..3
    const float* W = (g == 0) ? Wi : (g == 1) ? Wf : (g == 2) ? Wc : Wo;
    u16* dst = w_ws + (size_t)((g * 32 + nblk) * 32 + kblk) * (BNS * BK);
    const int nr = threadIdx.x & 31;   // n-row within tile
    const int s  = threadIdx.x >> 5;   // k-slot 0..7
    const int n  = nblk * 32 + nr;
    const float* p = W + (size_t)(kblk * 64 + s * 8) * 1024 + n;
    u16x8 o;
#pragma unroll
    for (int j = 0; j < 8; ++j) o[j] = f2b(p[(size_t)j * 1024]);
    *reinterpret_cast<u16x8*>(dst + nr * 64 + ((s ^ (nr & 7)) << 3)) = o;
}

// ---------------------------------------------------------------------------
// Fused 4-gate GEMM + LSTM epilogue. 256 thr (4 waves = 2M x 2N), tile
// 128m x 32n x 4g, BK=64, single-buffer 32 KiB LDS -> 4 blocks/CU. Simple
// stage -> sync -> compute -> sync loop; latency hidden by co-resident blocks.
// Wave w stages gate w's B tile (wave-uniform DMA dest).
// ---------------------------------------------------------------------------
__global__ __launch_bounds__(256, 4) void lstm_gemm_kernel(
    const u16* __restrict__ xh_ws, const u16* __restrict__ w_ws,
    const float* __restrict__ c_in,
    const float* __restrict__ b_i, const float* __restrict__ b_f,
    const float* __restrict__ b_c, const float* __restrict__ b_o,
    float* __restrict__ h_out, float* __restrict__ c_out) {
    __shared__ u16 lds[16384];     // A 128x64 (8192) + B 4 x 32x64 (8192) = 32 KiB
    u16* Al = lds;
    u16* Bl = lds + BM * BK;

    const int nblk = blockIdx.x;   // 0..31
    const int mblk = blockIdx.y;   // 0..31
    const int t    = threadIdx.x;
    const int lane = t & 63;
    const int w    = t >> 6;       // 0..3
    const int wm   = w >> 1;       // m-half 0..1 (64 rows)
    const int wn   = w & 1;        // n-half 0..1 (16 cols)
    const int l15  = lane & 15;
    const int l4   = lane >> 4;

    // staging sources (wave w stages gate w's B tile)
    const u16* aS = xh_ws + (size_t)mblk * (32 * 8192) + (w * 4) * 512 + lane * 8;
    const u16* bS = w_ws + (size_t)((w * 32 + nblk) * 32) * 2048 + lane * 8;
    u16* aD = Al + (w * 4) * 512;
    u16* bD = Bl + w * 2048;

    f32x4 acc[4][4] = {};          // [gate][mf]

    for (int kt = 0; kt < NT; ++kt) {
        // ---- stage: A 16 KiB + B 16 KiB, 8 gload16 per thread ----
#pragma unroll
        for (int i = 0; i < 4; ++i)
            gload16(aS + (size_t)kt * 8192 + i * 512, aD + i * 512);
#pragma unroll
        for (int i = 0; i < 4; ++i)
            gload16(bS + (size_t)kt * 2048 + i * 512, bD + i * 512);
        __syncthreads();

        // ---- compute: 2 k-steps of 32 ----
#pragma unroll
        for (int ks = 0; ks < 2; ++ks) {
            const int kc = ks * 4 + l4;
            short8 afr[4];
#pragma unroll
            for (int mf = 0; mf < 4; ++mf) {
                int row = wm * 64 + mf * 16 + l15;
                afr[mf] = *reinterpret_cast<const short8*>(
                    Al + row * 64 + (((kc ^ row) & 7) << 3));
            }
            const int n = wn * 16 + l15;
            const int bofs = n * 64 + (((kc ^ n) & 7) << 3);
#pragma unroll
            for (int g = 0; g < 4; ++g) {
                short8 bfr = *reinterpret_cast<const short8*>(Bl + g * 2048 + bofs);
#pragma unroll
                for (int mf = 0; mf < 4; ++mf)
                    acc[g][mf] = __builtin_amdgcn_mfma_f32_16x16x32_bf16(
                        afr[mf], bfr, acc[g][mf], 0, 0, 0);
            }
        }
        __syncthreads();
    }

    // ---- fused LSTM epilogue ----
    const int mBase = mblk * BM + wm * 64;
    const int n = nblk * BNS + wn * 16 + l15;
    const float vbi = b_i[n], vbf = b_f[n], vbc = b_c[n], vbo = b_o[n];
#pragma unroll
    for (int mf = 0; mf < 4; ++mf) {
#pragma unroll
        for (int r = 0; r < 4; ++r) {
            int m = mBase + mf * 16 + l4 * 4 + r;
            size_t idx = (size_t)m * NDIM + n;
            float gi = sigm(acc[G_I][mf][r] + vbi);
            float gf = sigm(acc[G_F][mf][r] + vbf);
            float gc = tanhf(acc[G_C][mf][r] + vbc);
            float go = sigm(acc[G_O][mf][r] + vbo);
            float ct = gf * c_in[idx] + gi * gc;
            h_out[idx] = go * tanhf(ct);
            c_out[idx] = ct;
        }
    }
}

extern "C" void kernel_launch(void* const* d_in, const int* in_sizes, int n_in,
                              void* d_out, int out_size, void* d_ws, size_t ws_size,
                              hipStream_t stream) {
    const float* x   = (const float*)d_in[0];
    const float* h   = (const float*)d_in[1];
    const float* c   = (const float*)d_in[2];
    const float* Wi  = (const float*)d_in[3];
    const float* Wf  = (const float*)d_in[4];
    const float* Wc  = (const float*)d_in[5];
    const float* Wo  = (const float*)d_in[6];
    const float* bi  = (const float*)d_in[7];
    const float* bf_ = (const float*)d_in[8];
    const float* bc  = (const float*)d_in[9];
    const float* bo  = (const float*)d_in[10];

    float* hout = (float*)d_out;
    float* cout = hout + (size_t)MDIM * NDIM;

    u16* xh_ws = (u16*)d_ws;                       // bf16 xh, 16.78 MB
    u16* w_ws  = xh_ws + (size_t)MDIM * KDIM;      // bf16 W^T, 16.78 MB

    conv_xh_kernel<<<dim3(32, 32), 256, 0, stream>>>(x, h, xh_ws);
    conv_w_kernel<<<dim3(32, 32, 4), 256, 0, stream>>>(Wi, Wf, Wc, Wo, w_ws);
    lstm_gemm_kernel<<<dim3(32, 32), 256, 0, stream>>>(
        xh_ws, w_ws, c, bi, bf_, bc, bo, hout, cout);
}